// Round 1
// baseline (2830.441 us; speedup 1.0000x reference)
//
#include <hip/hip_runtime.h>

#define NN 50000
#define NE 800000
#define IN_CH 128
#define HID 256
#define NG 1024
#define BN_EPS 1e-5f

// ---------------- degree / dinv ----------------
__global__ void init_deg(float* deg) {
    int i = blockIdx.x * blockDim.x + threadIdx.x;
    if (i < NN) deg[i] = 1.0f;   // self-loop contributes 1
}

__global__ void deg_edges(const int* __restrict__ dst, float* deg) {
    int e = blockIdx.x * blockDim.x + threadIdx.x;
    if (e < NE) atomicAdd(&deg[dst[e]], 1.0f);
}

__global__ void make_dinv(float* deg) {
    int i = blockIdx.x * blockDim.x + threadIdx.x;
    if (i < NN) deg[i] = rsqrtf(deg[i]);   // deg >= 1 always (self-loops)
}

// ---------------- GEMM: C[M,256] = A[M,K] @ W[K,256] (+bias) ----------------
// block = 256 threads = 4 waves. Tile: 32 rows x 256 cols.
// Wave w handles rows [8w, 8w+8); lane handles 4 consecutive cols (float4 W loads).
// A tile staged in LDS (reads are wave-broadcast -> conflict-free).
template <int K>
__global__ void gemm_bias_n256(const float* __restrict__ A,
                               const float* __restrict__ W,
                               const float* __restrict__ bias,
                               float* __restrict__ C, int M) {
    __shared__ float As[32][32];
    const int tid  = threadIdx.x;
    const int lane = tid & 63;
    const int wv   = tid >> 6;
    const int c0   = lane * 4;
    const int r0   = wv * 8;
    const int m0   = blockIdx.x * 32;

    float acc[8][4];
#pragma unroll
    for (int m = 0; m < 8; m++)
#pragma unroll
        for (int j = 0; j < 4; j++) acc[m][j] = 0.f;

    for (int kc = 0; kc < K; kc += 32) {
        __syncthreads();
#pragma unroll
        for (int i = 0; i < 4; i++) {
            int elem = tid + i * 256;          // 0..1023
            int r = elem >> 5, kk = elem & 31;
            int row = m0 + r;
            As[r][kk] = (row < M) ? A[row * K + kc + kk] : 0.f;
        }
        __syncthreads();
#pragma unroll
        for (int kk = 0; kk < 32; kk++) {
            const float4 w4 = *(const float4*)&W[(kc + kk) * 256 + c0];
#pragma unroll
            for (int m = 0; m < 8; m++) {
                float a = As[r0 + m][kk];
                acc[m][0] += a * w4.x;
                acc[m][1] += a * w4.y;
                acc[m][2] += a * w4.z;
                acc[m][3] += a * w4.w;
            }
        }
    }

    float4 bb = make_float4(0.f, 0.f, 0.f, 0.f);
    if (bias) bb = *(const float4*)&bias[c0];
#pragma unroll
    for (int m = 0; m < 8; m++) {
        int row = m0 + r0 + m;
        if (row < M) {
            float4 o;
            o.x = acc[m][0] + bb.x;
            o.y = acc[m][1] + bb.y;
            o.z = acc[m][2] + bb.z;
            o.w = acc[m][3] + bb.w;
            *(float4*)&C[row * 256 + c0] = o;
        }
    }
}

// ---------------- message passing ----------------
// agg[i,c] = hw[i,c]*dinv[i]^2 + bias[c]   (self-loop + conv bias, no atomics)
__global__ void selfloop_init(const float* __restrict__ hw,
                              const float* __restrict__ dinv,
                              const float* __restrict__ bias,
                              float* __restrict__ agg) {
    int idx = blockIdx.x * blockDim.x + threadIdx.x;
    if (idx >= NN * HID / 4) return;
    int base = idx * 4;
    int row = base >> 8;
    int c = base & 255;
    float w = dinv[row];
    w = w * w;
    float4 v = *(const float4*)&hw[base];
    float4 b = *(const float4*)&bias[c];
    float4 o;
    o.x = v.x * w + b.x;
    o.y = v.y * w + b.y;
    o.z = v.z * w + b.z;
    o.w = v.w * w + b.w;
    *(float4*)&agg[base] = o;
}

// agg[d,:] += hw[s,:] * dinv[s]*dinv[d]  for every edge
__global__ void edge_scatter(const int* __restrict__ src,
                             const int* __restrict__ dst,
                             const float* __restrict__ dinv,
                             const float* __restrict__ hw,
                             float* __restrict__ agg) {
    int c = threadIdx.x;
    for (int e = blockIdx.x; e < NE; e += gridDim.x) {
        int s = src[e], d = dst[e];
        float w = dinv[s] * dinv[d];
        atomicAdd(&agg[d * HID + c], hw[s * HID + c] * w);
    }
}

// ---------------- batchnorm ----------------
__global__ void bn_stats(const float* __restrict__ h, float* __restrict__ sum,
                         float* __restrict__ sumsq, int M) {
    int c = threadIdx.x;   // channel
    float s = 0.f, q = 0.f;
    for (int r = blockIdx.x; r < M; r += gridDim.x) {
        float v = h[r * HID + c];
        s += v;
        q += v * v;
    }
    atomicAdd(&sum[c], s);
    atomicAdd(&sumsq[c], q);
}

__global__ void bn_finalize(const float* __restrict__ sum,
                            const float* __restrict__ sumsq,
                            const float* __restrict__ gamma,
                            const float* __restrict__ beta,
                            float* __restrict__ scale, float* __restrict__ shift,
                            float invM) {
    int c = threadIdx.x;
    float mu = sum[c] * invM;
    float var = sumsq[c] * invM - mu * mu;
    float inv = rsqrtf(var + BN_EPS);
    float sc = inv * gamma[c];
    scale[c] = sc;
    shift[c] = beta[c] - mu * sc;
}

__global__ void bn_apply_relu(float* __restrict__ h,
                              const float* __restrict__ scale,
                              const float* __restrict__ shift, int M) {
    int idx = blockIdx.x * blockDim.x + threadIdx.x;
    if (idx >= M * HID / 4) return;
    int base = idx * 4;
    int c = base & 255;
    float4 v = *(float4*)&h[base];
    float4 sc = *(const float4*)&scale[c];
    float4 sh = *(const float4*)&shift[c];
    v.x = fmaxf(v.x * sc.x + sh.x, 0.f);
    v.y = fmaxf(v.y * sc.y + sh.y, 0.f);
    v.z = fmaxf(v.z * sc.z + sh.z, 0.f);
    v.w = fmaxf(v.w * sc.w + sh.w, 0.f);
    *(float4*)&h[base] = v;
}

// ---------------- pooling ----------------
__global__ void pool_sum(const float* __restrict__ h, const int* __restrict__ batch,
                         float* __restrict__ pooled, float* __restrict__ counts) {
    int c = threadIdx.x;
    for (int i = blockIdx.x; i < NN; i += gridDim.x) {
        int g = batch[i];
        atomicAdd(&pooled[g * HID + c], h[i * HID + c]);
        if (c == 0) atomicAdd(&counts[g], 1.0f);
    }
}

__global__ void pool_div(float* __restrict__ pooled, const float* __restrict__ counts) {
    int idx = blockIdx.x * blockDim.x + threadIdx.x;
    if (idx >= NG * HID) return;
    int g = idx >> 8;
    pooled[idx] /= fmaxf(counts[g], 1.0f);
}

// ---------------- final: out[g] = sum_c relu(bn(z[g,c]))*W2[c] + b2 ----------------
__global__ void final_out(const float* __restrict__ z, const float* __restrict__ scale,
                          const float* __restrict__ shift, const float* __restrict__ W2,
                          const float* __restrict__ b2, float* __restrict__ out) {
    int g = blockIdx.x;
    int c = threadIdx.x;
    float v = z[g * HID + c] * scale[c] + shift[c];
    v = fmaxf(v, 0.f) * W2[c];
    __shared__ float red[256];
    red[c] = v;
    __syncthreads();
    for (int s = 128; s > 0; s >>= 1) {
        if (c < s) red[c] += red[c + s];
        __syncthreads();
    }
    if (c == 0) out[g] = red[0] + b2[0];
}

// ---------------- launch ----------------
extern "C" void kernel_launch(void* const* d_in, const int* in_sizes, int n_in,
                              void* d_out, int out_size, void* d_ws, size_t ws_size,
                              hipStream_t stream) {
    const float* x      = (const float*)d_in[0];
    const int*   ei     = (const int*)d_in[1];   // [2, NE] (int32: JAX x64 disabled)
    const int*   batch  = (const int*)d_in[2];
    const float* W_emb  = (const float*)d_in[3];
    const float* b_emb  = (const float*)d_in[4];
    const float* W_conv = (const float*)d_in[5]; // [3,256,256]
    const float* b_conv = (const float*)d_in[6]; // [3,256]
    const float* gamma  = (const float*)d_in[7]; // [3,256]
    const float* beta   = (const float*)d_in[8]; // [3,256]
    const float* W1     = (const float*)d_in[9];
    const float* b1     = (const float*)d_in[10];
    const float* g2     = (const float*)d_in[11];
    const float* bt2    = (const float*)d_in[12];
    const float* W2     = (const float*)d_in[13];
    const float* b2     = (const float*)d_in[14];
    float* out = (float*)d_out;

    const int* src = ei;
    const int* dst = ei + NE;

    // workspace layout (floats)
    float* ws = (float*)d_ws;
    float* h      = ws;                        // NN*HID = 12.8M
    float* hw     = h + (size_t)NN * HID;      // NN*HID
    float* dinv   = hw + (size_t)NN * HID;     // NN
    float* stats  = dinv + NN;                 // 1024: sum, sumsq, scale, shift
    float* pooled = stats + 1024;              // NG*HID
    float* counts = pooled + (size_t)NG * HID; // NG
    float* ssum   = stats;
    float* ssq    = stats + 256;
    float* scale  = stats + 512;
    float* shift  = stats + 768;
    float* z      = hw;                        // reuse after last scatter

    const int B = 256;

    // degree / dinv (stored in dinv buffer)
    init_deg<<<(NN + B - 1) / B, B, 0, stream>>>(dinv);
    deg_edges<<<(NE + B - 1) / B, B, 0, stream>>>(dst, dinv);
    make_dinv<<<(NN + B - 1) / B, B, 0, stream>>>(dinv);

    // h = x @ W_emb + b_emb
    gemm_bias_n256<IN_CH><<<(NN + 31) / 32, B, 0, stream>>>(x, W_emb, b_emb, h, NN);

    for (int l = 0; l < 3; l++) {
        const float* Wl = W_conv + (size_t)l * HID * HID;
        const float* bl = b_conv + (size_t)l * HID;
        // hw = h @ Wl
        gemm_bias_n256<HID><<<(NN + 31) / 32, B, 0, stream>>>(h, Wl, nullptr, hw, NN);
        // agg (in h) = selfloop + bias, then scatter edges
        selfloop_init<<<(NN * HID / 4 + B - 1) / B, B, 0, stream>>>(hw, dinv, bl, h);
        edge_scatter<<<16384, B, 0, stream>>>(src, dst, dinv, hw, h);
        // batchnorm + relu in place on h
        hipMemsetAsync(stats, 0, 512 * sizeof(float), stream);
        bn_stats<<<256, B, 0, stream>>>(h, ssum, ssq, NN);
        bn_finalize<<<1, B, 0, stream>>>(ssum, ssq, gamma + l * HID, beta + l * HID,
                                         scale, shift, 1.0f / NN);
        bn_apply_relu<<<(NN * HID / 4 + B - 1) / B, B, 0, stream>>>(h, scale, shift, NN);
    }

    // global mean pool
    hipMemsetAsync(pooled, 0, (size_t)NG * HID * sizeof(float), stream);
    hipMemsetAsync(counts, 0, NG * sizeof(float), stream);
    pool_sum<<<16384, B, 0, stream>>>(h, batch, pooled, counts);
    pool_div<<<(NG * HID + B - 1) / B, B, 0, stream>>>(pooled, counts);

    // z = pooled @ W1 + b1
    gemm_bias_n256<HID><<<(NG + 31) / 32, B, 0, stream>>>(pooled, W1, b1, z, NG);

    // bn2 + relu + head
    hipMemsetAsync(stats, 0, 512 * sizeof(float), stream);
    bn_stats<<<256, B, 0, stream>>>(z, ssum, ssq, NG);
    bn_finalize<<<1, B, 0, stream>>>(ssum, ssq, g2, bt2, scale, shift, 1.0f / NG);
    final_out<<<NG, B, 0, stream>>>(z, scale, shift, W2, b2, out);
}

// Round 2
// 1397.643 us; speedup vs baseline: 2.0252x; 2.0252x over previous
//
#include <hip/hip_runtime.h>

#define NN 50000
#define NE 800000
#define IN_CH 128
#define HID 256
#define NG 1024
#define BN_EPS 1e-5f

// ---------------- CSR build ----------------
__global__ void hist_dst(const int* __restrict__ dst, int* __restrict__ cnt) {
    int e = blockIdx.x * blockDim.x + threadIdx.x;
    if (e < NE) atomicAdd(&cnt[dst[e]], 1);
}

// single block, 1024 threads: exclusive scan of cnt -> row_ptr & cursor; dinv.
__global__ void scan_build(const int* __restrict__ cnt, int* __restrict__ row_ptr,
                           int* __restrict__ cursor, float* __restrict__ dinv) {
    __shared__ int part[1024];
    const int t = threadIdx.x;
    const int CH = (NN + 1023) / 1024;   // 49
    const int lo = t * CH;
    const int hi = (lo + CH < NN) ? lo + CH : NN;
    int s = 0;
    for (int i = lo; i < hi; i++) s += cnt[i];
    part[t] = s;
    __syncthreads();
    for (int off = 1; off < 1024; off <<= 1) {
        int v = (t >= off) ? part[t - off] : 0;
        __syncthreads();
        part[t] += v;
        __syncthreads();
    }
    int run = (t == 0) ? 0 : part[t - 1];
    for (int i = lo; i < hi; i++) {
        int ci = cnt[i];
        row_ptr[i] = run;
        cursor[i] = run;
        dinv[i] = rsqrtf(1.0f + (float)ci);   // deg includes self-loop
        run += ci;
    }
    if (t == 0) row_ptr[NN] = NE;
}

__global__ void csr_fill(const int* __restrict__ src, const int* __restrict__ dst,
                         const float* __restrict__ dinv, int* __restrict__ cursor,
                         int* __restrict__ src_sorted, float* __restrict__ w_sorted) {
    int e = blockIdx.x * blockDim.x + threadIdx.x;
    if (e >= NE) return;
    int s = src[e], d = dst[e];
    int pos = atomicAdd(&cursor[d], 1);
    src_sorted[pos] = s;
    w_sorted[pos] = dinv[s] * dinv[d];
}

// ---------------- GEMM: C[M,256] = A[M,K] @ W[K,256] (+bias) ----------------
template <int K>
__global__ void gemm_bias_n256(const float* __restrict__ A,
                               const float* __restrict__ W,
                               const float* __restrict__ bias,
                               float* __restrict__ C, int M) {
    __shared__ float As[32][32];
    const int tid  = threadIdx.x;
    const int lane = tid & 63;
    const int wv   = tid >> 6;
    const int c0   = lane * 4;
    const int r0   = wv * 8;
    const int m0   = blockIdx.x * 32;

    float acc[8][4];
#pragma unroll
    for (int m = 0; m < 8; m++)
#pragma unroll
        for (int j = 0; j < 4; j++) acc[m][j] = 0.f;

    for (int kc = 0; kc < K; kc += 32) {
        __syncthreads();
#pragma unroll
        for (int i = 0; i < 4; i++) {
            int elem = tid + i * 256;
            int r = elem >> 5, kk = elem & 31;
            int row = m0 + r;
            As[r][kk] = (row < M) ? A[row * K + kc + kk] : 0.f;
        }
        __syncthreads();
#pragma unroll
        for (int kk = 0; kk < 32; kk++) {
            const float4 w4 = *(const float4*)&W[(kc + kk) * 256 + c0];
#pragma unroll
            for (int m = 0; m < 8; m++) {
                float a = As[r0 + m][kk];
                acc[m][0] += a * w4.x;
                acc[m][1] += a * w4.y;
                acc[m][2] += a * w4.z;
                acc[m][3] += a * w4.w;
            }
        }
    }

    float4 bb = make_float4(0.f, 0.f, 0.f, 0.f);
    if (bias) bb = *(const float4*)&bias[c0];
#pragma unroll
    for (int m = 0; m < 8; m++) {
        int row = m0 + r0 + m;
        if (row < M) {
            float4 o;
            o.x = acc[m][0] + bb.x;
            o.y = acc[m][1] + bb.y;
            o.z = acc[m][2] + bb.z;
            o.w = acc[m][3] + bb.w;
            *(float4*)&C[row * 256 + c0] = o;
        }
    }
}

// ---------------- pull-based aggregation ----------------
// block = 256 threads = 4 waves; wave handles one node; lane owns 4 channels.
// outh[d,:] = hw[d,:]*dinv[d]^2 + bias + sum_e hw[src[e],:]*w[e]
__global__ void gcn_aggregate(const float* __restrict__ hw,
                              const int* __restrict__ row_ptr,
                              const int* __restrict__ src_sorted,
                              const float* __restrict__ w_sorted,
                              const float* __restrict__ dinv,
                              const float* __restrict__ bias,
                              float* __restrict__ outh) {
    const int wv   = threadIdx.x >> 6;
    const int lane = threadIdx.x & 63;
    const int d    = blockIdx.x * 4 + wv;     // NN % 4 == 0
    const int c0   = lane * 4;

    float di = dinv[d];
    float sl = di * di;
    float4 b = *(const float4*)&bias[c0];
    float4 v = *(const float4*)&hw[d * HID + c0];
    float4 acc;
    acc.x = v.x * sl + b.x;
    acc.y = v.y * sl + b.y;
    acc.z = v.z * sl + b.z;
    acc.w = v.w * sl + b.w;

    int e  = row_ptr[d];
    int e1 = row_ptr[d + 1];
    for (; e + 2 <= e1; e += 2) {
        int   s0 = src_sorted[e];
        int   s1 = src_sorted[e + 1];
        float w0 = w_sorted[e];
        float w1 = w_sorted[e + 1];
        float4 a0 = *(const float4*)&hw[s0 * HID + c0];
        float4 a1 = *(const float4*)&hw[s1 * HID + c0];
        acc.x += a0.x * w0 + a1.x * w1;
        acc.y += a0.y * w0 + a1.y * w1;
        acc.z += a0.z * w0 + a1.z * w1;
        acc.w += a0.w * w0 + a1.w * w1;
    }
    if (e < e1) {
        int   s0 = src_sorted[e];
        float w0 = w_sorted[e];
        float4 a0 = *(const float4*)&hw[s0 * HID + c0];
        acc.x += a0.x * w0;
        acc.y += a0.y * w0;
        acc.z += a0.z * w0;
        acc.w += a0.w * w0;
    }
    *(float4*)&outh[d * HID + c0] = acc;
}

// ---------------- batchnorm ----------------
__global__ void bn_stats(const float* __restrict__ h, float* __restrict__ sum,
                         float* __restrict__ sumsq, int M) {
    int c = threadIdx.x;
    float s = 0.f, q = 0.f;
    for (int r = blockIdx.x; r < M; r += gridDim.x) {
        float v = h[r * HID + c];
        s += v;
        q += v * v;
    }
    atomicAdd(&sum[c], s);
    atomicAdd(&sumsq[c], q);
}

__global__ void bn_finalize(const float* __restrict__ sum,
                            const float* __restrict__ sumsq,
                            const float* __restrict__ gamma,
                            const float* __restrict__ beta,
                            float* __restrict__ scale, float* __restrict__ shift,
                            float invM) {
    int c = threadIdx.x;
    float mu = sum[c] * invM;
    float var = sumsq[c] * invM - mu * mu;
    float inv = rsqrtf(var + BN_EPS);
    float sc = inv * gamma[c];
    scale[c] = sc;
    shift[c] = beta[c] - mu * sc;
}

__global__ void bn_apply_relu(float* __restrict__ h,
                              const float* __restrict__ scale,
                              const float* __restrict__ shift, int M) {
    int idx = blockIdx.x * blockDim.x + threadIdx.x;
    if (idx >= M * HID / 4) return;
    int base = idx * 4;
    int c = base & 255;
    float4 v = *(float4*)&h[base];
    float4 sc = *(const float4*)&scale[c];
    float4 sh = *(const float4*)&shift[c];
    v.x = fmaxf(v.x * sc.x + sh.x, 0.f);
    v.y = fmaxf(v.y * sc.y + sh.y, 0.f);
    v.z = fmaxf(v.z * sc.z + sh.z, 0.f);
    v.w = fmaxf(v.w * sc.w + sh.w, 0.f);
    *(float4*)&h[base] = v;
}

// ---------------- pooling ----------------
__global__ void pool_sum(const float* __restrict__ h, const int* __restrict__ batch,
                         float* __restrict__ pooled, float* __restrict__ counts) {
    int c = threadIdx.x;
    for (int i = blockIdx.x; i < NN; i += gridDim.x) {
        int g = batch[i];
        atomicAdd(&pooled[g * HID + c], h[i * HID + c]);
        if (c == 0) atomicAdd(&counts[g], 1.0f);
    }
}

__global__ void pool_div(float* __restrict__ pooled, const float* __restrict__ counts) {
    int idx = blockIdx.x * blockDim.x + threadIdx.x;
    if (idx >= NG * HID) return;
    int g = idx >> 8;
    pooled[idx] /= fmaxf(counts[g], 1.0f);
}

// ---------------- head ----------------
__global__ void final_out(const float* __restrict__ z, const float* __restrict__ scale,
                          const float* __restrict__ shift, const float* __restrict__ W2,
                          const float* __restrict__ b2, float* __restrict__ out) {
    int g = blockIdx.x;
    int c = threadIdx.x;
    float v = z[g * HID + c] * scale[c] + shift[c];
    v = fmaxf(v, 0.f) * W2[c];
    __shared__ float red[256];
    red[c] = v;
    __syncthreads();
    for (int s = 128; s > 0; s >>= 1) {
        if (c < s) red[c] += red[c + s];
        __syncthreads();
    }
    if (c == 0) out[g] = red[0] + b2[0];
}

// ---------------- launch ----------------
extern "C" void kernel_launch(void* const* d_in, const int* in_sizes, int n_in,
                              void* d_out, int out_size, void* d_ws, size_t ws_size,
                              hipStream_t stream) {
    const float* x      = (const float*)d_in[0];
    const int*   ei     = (const int*)d_in[1];
    const int*   batch  = (const int*)d_in[2];
    const float* W_emb  = (const float*)d_in[3];
    const float* b_emb  = (const float*)d_in[4];
    const float* W_conv = (const float*)d_in[5];
    const float* b_conv = (const float*)d_in[6];
    const float* gamma  = (const float*)d_in[7];
    const float* beta   = (const float*)d_in[8];
    const float* W1     = (const float*)d_in[9];
    const float* b1     = (const float*)d_in[10];
    const float* g2     = (const float*)d_in[11];
    const float* bt2    = (const float*)d_in[12];
    const float* W2     = (const float*)d_in[13];
    const float* b2     = (const float*)d_in[14];
    float* out = (float*)d_out;

    const int* src = ei;
    const int* dst = ei + NE;

    // workspace layout
    float* ws = (float*)d_ws;
    float* h          = ws;                          // 12.8M f
    float* hw         = h + (size_t)NN * HID;        // 12.8M f
    float* dinv       = hw + (size_t)NN * HID;       // NN
    float* stats      = dinv + NN;                   // 1024
    int*   cnt        = (int*)(stats + 1024);        // NN
    int*   row_ptr    = cnt + NN;                    // NN+1
    int*   cursor     = row_ptr + NN + 1;            // NN
    int*   src_sorted = cursor + NN;                 // NE
    float* w_sorted   = (float*)(src_sorted + NE);   // NE
    // pooled/counts alias w_sorted region? w_sorted used until layer-3 agg,
    // pooling happens strictly after -> safe to alias.
    float* pooled = (float*)(src_sorted);            // NG*HID = 262144 f <= NE ints
    float* counts = w_sorted + 0;                    // reuse w_sorted start for counts
    float* ssum  = stats;
    float* ssq   = stats + 256;
    float* scale = stats + 512;
    float* shift = stats + 768;
    float* z     = hw;   // reuse after last aggregation

    const int B = 256;

    // CSR build (per call; workspace is re-poisoned every launch)
    hipMemsetAsync(cnt, 0, NN * sizeof(int), stream);
    hist_dst<<<(NE + B - 1) / B, B, 0, stream>>>(dst, cnt);
    scan_build<<<1, 1024, 0, stream>>>(cnt, row_ptr, cursor, dinv);
    csr_fill<<<(NE + B - 1) / B, B, 0, stream>>>(src, dst, dinv, cursor,
                                                 src_sorted, w_sorted);

    // h = x @ W_emb + b_emb
    gemm_bias_n256<IN_CH><<<(NN + 31) / 32, B, 0, stream>>>(x, W_emb, b_emb, h, NN);

    for (int l = 0; l < 3; l++) {
        const float* Wl = W_conv + (size_t)l * HID * HID;
        const float* bl = b_conv + (size_t)l * HID;
        gemm_bias_n256<HID><<<(NN + 31) / 32, B, 0, stream>>>(h, Wl, nullptr, hw, NN);
        gcn_aggregate<<<NN / 4, B, 0, stream>>>(hw, row_ptr, src_sorted, w_sorted,
                                                dinv, bl, h);
        hipMemsetAsync(stats, 0, 512 * sizeof(float), stream);
        bn_stats<<<256, B, 0, stream>>>(h, ssum, ssq, NN);
        bn_finalize<<<1, B, 0, stream>>>(ssum, ssq, gamma + l * HID, beta + l * HID,
                                         scale, shift, 1.0f / NN);
        bn_apply_relu<<<(NN * HID / 4 + B - 1) / B, B, 0, stream>>>(h, scale, shift, NN);
    }

    // global mean pool (pooled aliases CSR region — CSR no longer needed)
    hipMemsetAsync(pooled, 0, (size_t)NG * HID * sizeof(float), stream);
    hipMemsetAsync(counts, 0, NG * sizeof(float), stream);
    pool_sum<<<16384, B, 0, stream>>>(h, batch, pooled, counts);
    pool_div<<<(NG * HID + B - 1) / B, B, 0, stream>>>(pooled, counts);

    // z = pooled @ W1 + b1
    gemm_bias_n256<HID><<<(NG + 31) / 32, B, 0, stream>>>(pooled, W1, b1, z, NG);

    hipMemsetAsync(stats, 0, 512 * sizeof(float), stream);
    bn_stats<<<256, B, 0, stream>>>(z, ssum, ssq, NG);
    bn_finalize<<<1, B, 0, stream>>>(ssum, ssq, g2, bt2, scale, shift, 1.0f / NG);
    final_out<<<NG, B, 0, stream>>>(z, scale, shift, W2, b2, out);
}